// Round 8
// baseline (186.750 us; speedup 1.0000x reference)
//
#include <hip/hip_runtime.h>
#include <stddef.h>

typedef __attribute__((ext_vector_type(8))) short short8;
typedef __attribute__((ext_vector_type(4))) float f32x4;
typedef __attribute__((ext_vector_type(2))) unsigned int u32x2;
typedef __attribute__((ext_vector_type(4))) unsigned int u32x4;
typedef unsigned short ushort_t;
typedef unsigned int uint_t;

#define TT 1024
#define NT 131072.0f   // N*T
#define EPS 1e-5f

__device__ __forceinline__ float bf2f(ushort_t u){
    union { float f; uint_t i; } v; v.i = ((uint_t)u) << 16; return v.f;
}
__device__ __forceinline__ ushort_t f2bf(float f){
    union { float f; uint_t i; } v; v.f = f;
    uint_t r = v.i + 0x7fffu + ((v.i >> 16) & 1u);
    return (ushort_t)(r >> 16);
}
__device__ __forceinline__ uint_t pack2(float lo, float hi){
    return (uint_t)f2bf(lo) | ((uint_t)f2bf(hi) << 16);
}
__device__ __forceinline__ f32x4 ld4bf(const ushort_t* p){
    u32x2 u = *(const u32x2*)p;
    f32x4 r;
    r[0] = bf2f((ushort_t)(u[0] & 0xffffu));
    r[1] = bf2f((ushort_t)(u[0] >> 16));
    r[2] = bf2f((ushort_t)(u[1] & 0xffffu));
    r[3] = bf2f((ushort_t)(u[1] >> 16));
    return r;
}
__device__ __forceinline__ void ld8bf(const ushort_t* p, f32x4& lo, f32x4& hi){
    u32x4 u = *(const u32x4*)p;
    lo[0] = bf2f((ushort_t)(u[0] & 0xffffu)); lo[1] = bf2f((ushort_t)(u[0] >> 16));
    lo[2] = bf2f((ushort_t)(u[1] & 0xffffu)); lo[3] = bf2f((ushort_t)(u[1] >> 16));
    hi[0] = bf2f((ushort_t)(u[2] & 0xffffu)); hi[1] = bf2f((ushort_t)(u[2] >> 16));
    hi[2] = bf2f((ushort_t)(u[3] & 0xffffu)); hi[3] = bf2f((ushort_t)(u[3] >> 16));
}
__device__ __forceinline__ void wave_red(float& v){
    #pragma unroll
    for (int off = 32; off > 0; off >>= 1) v += __shfl_down(v, off);
}
// async 16B global->LDS (width-16 DMA). LDS dest = wave-uniform base + lane*16.
__device__ __forceinline__ void dma16(const void* g, void* l){
    __builtin_amdgcn_global_load_lds(
        (const __attribute__((address_space(1))) unsigned int*)g,
        (__attribute__((address_space(3))) unsigned int*)l, 16, 0, 0);
}

// ---- Pass 1: per-channel stats of RAW x + shifted raw-x bf16 (pre-swizzled) ---
// grid 512, 4-tile stride. Tile tb: 64 flat rows. Thread: 8 ch x 8 rows.
__global__ __launch_bounds__(256) void k_prep(const float* __restrict__ x,
                                              const float* __restrict__ sin_,
                                              ushort_t* __restrict__ xs,
                                              float* __restrict__ psum,
                                              float* __restrict__ psq){
    __shared__ float ls[8][256], lq[8][256];
    const int tid = threadIdx.x;
    const int c8 = (tid & 31) << 3, rg = tid >> 5;
    float a0[8], a1[8]; int i1[8];
    #pragma unroll
    for (int j = 0; j < 8; ++j){
        float sv = sin_[c8 + j]; float fi = floorf(sv); float fr = sv - fi;
        a0[j] = 1.f - fr; a1[j] = fr; i1[j] = (int)fi + 1;
    }
    for (int g = 0; g < 4; ++g){
        const int tb = blockIdx.x + (g << 9);
        const size_t row0 = ((size_t)tb << 6) + ((size_t)rg << 3);
        const int n = (int)(row0 >> 10), rt = (int)(row0 & 1023);
        const float* xp = x + ((size_t)n << 18) + c8;
        ushort_t* wp = xs + ((size_t)n << 18);
        f32x4 s0 = {0.f,0.f,0.f,0.f}, s1v = s0, q0 = s0, q1 = s0;
        f32x4 Am = s0, Bm = s0, A0 = s0, B0 = s0;
        if (rt > 0){
            Am = *(const f32x4*)&xp[(size_t)(rt - 1) << 8];
            Bm = *(const f32x4*)&xp[((size_t)(rt - 1) << 8) + 4];
        }
        A0 = *(const f32x4*)&xp[(size_t)rt << 8];
        B0 = *(const f32x4*)&xp[((size_t)rt << 8) + 4];
        #pragma unroll
        for (int k = 0; k < 8; ++k){
            const int t = rt + k;
            f32x4 Ap = {0.f,0.f,0.f,0.f}, Bp = Ap;
            if (t < 1023){
                Ap = *(const f32x4*)&xp[(size_t)(t + 1) << 8];
                Bp = *(const f32x4*)&xp[((size_t)(t + 1) << 8) + 4];
            }
            float v[8];
            #pragma unroll
            for (int j = 0; j < 4; ++j){
                s0[j] += A0[j]; q0[j] = fmaf(A0[j], A0[j], q0[j]);
                s1v[j] += B0[j]; q1[j] = fmaf(B0[j], B0[j], q1[j]);
                float zl = i1[j] ? A0[j] : Am[j];
                float zr = i1[j] ? Ap[j] : A0[j];
                v[j] = a0[j] * zl + a1[j] * zr;
                float zl2 = i1[4 + j] ? B0[j] : Bm[j];
                float zr2 = i1[4 + j] ? Bp[j] : B0[j];
                v[4 + j] = a0[4 + j] * zl2 + a1[4 + j] * zr2;
            }
            u32x4 u;
            u[0] = pack2(v[0], v[1]); u[1] = pack2(v[2], v[3]);
            u[2] = pack2(v[4], v[5]); u[3] = pack2(v[6], v[7]);
            *(u32x4*)&wp[((size_t)t << 8) + (c8 ^ ((t & 7) << 3))] = u;
            Am = A0; Bm = B0; A0 = Ap; B0 = Bp;
        }
        #pragma unroll
        for (int j = 0; j < 4; ++j){
            ls[rg][c8 + j] = s0[j];     lq[rg][c8 + j] = q0[j];
            ls[rg][c8 + 4 + j] = s1v[j]; lq[rg][c8 + 4 + j] = q1[j];
        }
        __syncthreads();
        const int c = tid;
        float ps = 0.f, pq = 0.f;
        #pragma unroll
        for (int gg = 0; gg < 8; ++gg){ ps += ls[gg][c]; pq += lq[gg][c]; }
        psum[(size_t)tb * 256 + c] = ps;
        psq [(size_t)tb * 256 + c] = pq;
        __syncthreads();   // protect ls/lq reuse next tile
    }
}

// grid 256 (channel), block 256: reduce 2048 partials -> BN1 affine.
__global__ __launch_bounds__(256) void k_fin1(const float* __restrict__ psum,
                                              const float* __restrict__ psq,
                                              const float* __restrict__ g1,
                                              const float* __restrict__ be1,
                                              float* __restrict__ s1, float* __restrict__ b1){
    const int c = blockIdx.x, t = threadIdx.x;
    float s = 0.f, q = 0.f;
    #pragma unroll
    for (int i = 0; i < 8; ++i){
        const size_t b = (size_t)(t * 8 + i);
        s += psum[b * 256 + c]; q += psq[b * 256 + c];
    }
    wave_red(s); wave_red(q);
    __shared__ float sm[8];
    const int wv = t >> 6, ln = t & 63;
    if (ln == 0){ sm[wv] = s; sm[4 + wv] = q; }
    __syncthreads();
    if (t == 0){
        float S = sm[0] + sm[1] + sm[2] + sm[3];
        float Q = sm[4] + sm[5] + sm[6] + sm[7];
        float mean = S / NT;
        float var  = Q / NT - mean * mean;
        float rstd = rsqrtf(var + EPS);
        float sc = rstd * g1[c];
        s1[c] = sc;
        b1[c] = be1[c] - mean * sc;
    }
}

// ---- merged: WF fragments (W*s1 bf16) + bias2/corr0/corrT. grid 256 (o). ----
__global__ __launch_bounds__(256) void k_w(const float* __restrict__ W,
                                           const float* __restrict__ cb,
                                           const float* __restrict__ s1,
                                           const float* __restrict__ b1,
                                           const float* __restrict__ sin_,
                                           ushort_t* __restrict__ WF,
                                           float* __restrict__ bias2,
                                           float* __restrict__ corr0,
                                           float* __restrict__ corrT){
    const int o = blockIdx.x, c = threadIdx.x;
    const float w = W[(size_t)o * 256 + c];
    float sv = sin_[c]; float fi = floorf(sv); float fr = sv - fi;
    const float a0 = 1.f - fr, a1 = fr; const int i1 = (int)fi + 1;
    // fragment-major scatter: row=o, k=c
    const int ks = c >> 5, lg = (c & 31) >> 3, j = c & 7;
    WF[(size_t)(((ks * 16 + (o >> 4)) * 64 + lg * 16 + (o & 15)) * 8 + j)] = f2bf(w * s1[c]);
    float wb = w * b1[c];
    float c0 = (i1 == 0) ? wb * a0 : 0.f;
    float cT = (i1 == 1) ? wb * a1 : 0.f;
    wave_red(wb); wave_red(c0); wave_red(cT);
    __shared__ float sm[4][3];
    const int wv = c >> 6, ln = c & 63;
    if (ln == 0){ sm[wv][0] = wb; sm[wv][1] = c0; sm[wv][2] = cT; }
    __syncthreads();
    if (c == 0){
        bias2[o] = cb[o] + sm[0][0] + sm[1][0] + sm[2][0] + sm[3][0];
        corr0[o] = sm[0][1] + sm[1][1] + sm[2][1] + sm[3][1];
        corrT[o] = sm[0][2] + sm[1][2] + sm[2][2] + sm[3][2];
    }
}

// -------- Pass 2: GEMM (2-phase vmcnt staging) + bias/relu + BN2 partials ------
// grid 512, 4-tile stride. Tile = (n, 64 t-rows). block 256 (4 waves). LDS 32 KB.
__global__ __launch_bounds__(256) void k_conv(const ushort_t* __restrict__ xs,
                                              const ushort_t* __restrict__ WF,
                                              const float* __restrict__ bias2,
                                              const float* __restrict__ corr0,
                                              const float* __restrict__ corrT,
                                              ushort_t* __restrict__ Y,
                                              float* __restrict__ SP, float* __restrict__ SQ,
                                              float* __restrict__ SR,
                                              float* __restrict__ FR, float* __restrict__ LR){
    __shared__ __align__(16) ushort_t lds[16384];   // 64 rows x 256 ush (swizzled)
    const int tid = threadIdx.x;
    const int lane = tid & 63, wv = tid >> 6;
    const int l15 = lane & 15, lg = lane >> 4;
    const short8* wf8 = (const short8*)WF;

    for (int g = 0; g < 4; ++g){
        const int tb = blockIdx.x + (g << 9);
        const int n  = tb >> 4;
        const int t0 = (tb & 15) << 6;
        __syncthreads();   // LDS reuse fence; also drains vmcnt to 0

        // ---- staging: half1 = rows [wv*8, wv*8+8), half2 = +32 ----
        {
            const ushort_t* gsrc = xs + ((size_t)n << 18) + ((size_t)(t0 + (wv << 3)) << 8);
            #pragma unroll
            for (int i = 0; i < 4; ++i)
                dma16(gsrc + (i << 9) + (lane << 3), &lds[(wv << 11) + (i << 9)]);
            const ushort_t* gsrc2 = gsrc + (32 << 8);
            #pragma unroll
            for (int i = 0; i < 4; ++i)
                dma16(gsrc2 + (i << 9) + (lane << 3), &lds[8192 + (wv << 11) + (i << 9)]);
        }

        // ---- MFMA: out tile 256(o) x 64(t); phase A: t<32, phase B: t>=32 ----
        f32x4 acc[4][4];
        #pragma unroll
        for (int r = 0; r < 4; ++r)
            #pragma unroll
            for (int q = 0; q < 4; ++q)
                acc[r][q] = (f32x4){0.f, 0.f, 0.f, 0.f};

        #pragma unroll
        for (int half = 0; half < 2; ++half){
            if (half == 0) { asm volatile("s_waitcnt vmcnt(4)" ::: "memory"); }
            else           { asm volatile("s_waitcnt vmcnt(0)" ::: "memory"); }
            __builtin_amdgcn_sched_barrier(0);
            __builtin_amdgcn_s_barrier();
            #pragma unroll
            for (int ks = 0; ks < 8; ++ks){
                short8 aF[4], bF[2];
                #pragma unroll
                for (int r = 0; r < 4; ++r)
                    aF[r] = wf8[(ks * 16 + wv * 4 + r) * 64 + lane];
                const int kk = (ks << 5) + (lg << 3);
                #pragma unroll
                for (int qq = 0; qq < 2; ++qq){
                    const int t = ((half * 2 + qq) << 4) | l15;
                    bF[qq] = *(const short8*)&lds[(t << 8) + (kk ^ ((t & 7) << 3))];
                }
                #pragma unroll
                for (int r = 0; r < 4; ++r)
                    #pragma unroll
                    for (int qq = 0; qq < 2; ++qq)
                        acc[r][half * 2 + qq] =
                            __builtin_amdgcn_mfma_f32_16x16x32_bf16(aF[r], bF[qq],
                                                                    acc[r][half * 2 + qq], 0, 0, 0);
            }
        }
        __syncthreads();

        // ---- epilogue: bias + boundary corr + relu -> LDS [t][o ^ ((t&7)<<3)] ----
        const bool isFirst = (t0 == 0), isLast = (t0 == 960);
        #pragma unroll
        for (int r = 0; r < 4; ++r){
            const int ob = (wv << 6) + (r << 4) + (lg << 2);
            const f32x4 cbv = *(const f32x4*)&bias2[ob];
            f32x4 c0v = {0.f,0.f,0.f,0.f}, cTv = {0.f,0.f,0.f,0.f};
            if (isFirst) c0v = *(const f32x4*)&corr0[ob];
            if (isLast)  cTv = *(const f32x4*)&corrT[ob];
            #pragma unroll
            for (int q = 0; q < 4; ++q){
                const int t = (q << 4) | l15;
                float v[4];
                #pragma unroll
                for (int j = 0; j < 4; ++j){
                    float z = acc[r][q][j] + cbv[j];
                    if (isFirst && t == 0)  z -= c0v[j];
                    if (isLast  && t == 63) z -= cTv[j];
                    v[j] = z > 0.f ? z : 0.f;
                }
                u32x2 w; w[0] = pack2(v[0], v[1]); w[1] = pack2(v[2], v[3]);
                *(u32x2*)&lds[(t << 8) + (ob ^ ((t & 7) << 3))] = w;
            }
        }
        __syncthreads();

        // ---- Y store (coalesced, de-swizzle on read) + FR/LR + in-tile stats ----
        u32x2* Yu = (u32x2*)Y;
        const size_t rbase = ((size_t)n << 10) + t0;
        #pragma unroll
        for (int it = 0; it < 16; ++it){
            const int row = (it << 2) + wv;
            u32x2 v = *(const u32x2*)&lds[(row << 8) + ((lane << 2) ^ ((row & 7) << 3))];
            Yu[((rbase + row) << 6) + lane] = v;
        }
        {
            const int o = tid;
            FR[(size_t)tb * 256 + o] = bf2f(lds[o]);
            LR[(size_t)tb * 256 + o] = bf2f(lds[(63 << 8) + (o ^ 56)]);
        }
        f32x4 P = {0.f,0.f,0.f,0.f}, Q = P, R = P;
        {
            const int o4 = lane << 2;
            const int r0 = wv << 4;
            f32x4 prev = {0.f,0.f,0.f,0.f};
            if (wv > 0) prev = ld4bf(&lds[((r0 - 1) << 8) + (o4 ^ (((r0 - 1) & 7) << 3))]);
            #pragma unroll 8
            for (int k = 0; k < 16; ++k){
                const int t = r0 + k;
                f32x4 y = ld4bf(&lds[(t << 8) + (o4 ^ ((t & 7) << 3))]);
                #pragma unroll
                for (int j = 0; j < 4; ++j){
                    P[j] += y[j];
                    Q[j] = fmaf(y[j], y[j], Q[j]);
                    R[j] = fmaf(prev[j], y[j], R[j]);
                }
                prev = y;
            }
        }
        __syncthreads();
        float* fl = (float*)lds;
        {
            const int o4 = lane << 2;
            *(f32x4*)&fl[wv * 768 + o4]       = P;
            *(f32x4*)&fl[wv * 768 + 256 + o4] = Q;
            *(f32x4*)&fl[wv * 768 + 512 + o4] = R;
        }
        __syncthreads();
        {
            const int o = tid;
            float p = fl[o] + fl[768 + o] + fl[1536 + o] + fl[2304 + o];
            float q = fl[256 + o] + fl[1024 + o] + fl[1792 + o] + fl[2560 + o];
            float r = fl[512 + o] + fl[1280 + o] + fl[2048 + o] + fl[2816 + o];
            const size_t idx = (size_t)tb * 256 + o;
            SP[idx] = p; SQ[idx] = q; SR[idx] = r;
        }
    }
}

// ---------------- Pass 3: assemble shifted BN2 stats ---------------------------
__global__ __launch_bounds__(256) void k_fin2(const float* __restrict__ SP,
                                              const float* __restrict__ SQ,
                                              const float* __restrict__ SR,
                                              const float* __restrict__ FR,
                                              const float* __restrict__ LR,
                                              const float* __restrict__ g2,
                                              const float* __restrict__ be2,
                                              const float* __restrict__ sout,
                                              float* __restrict__ s2, float* __restrict__ b2){
    const int o = blockIdx.x, t = threadIdx.x;
    float P = 0.f, Q = 0.f, R = 0.f, b0p = 0.f, b0q = 0.f, btp = 0.f, btq = 0.f;
    #pragma unroll
    for (int i = 0; i < 8; ++i){
        const int b = t * 8 + i;
        const size_t idx = (size_t)b * 256 + o;
        P += SP[idx]; Q += SQ[idx];
        float r = SR[idx];
        const float fr = FR[idx], lr = LR[idx];
        const int tile = b & 15;
        if (tile > 0) r = fmaf(LR[idx - 256], fr, r);
        R += r;
        if (tile == 0){ b0p += fr; b0q += fr * fr; }
        if (tile == 15){ btp += lr; btq += lr * lr; }
    }
    wave_red(P); wave_red(Q); wave_red(R);
    wave_red(b0p); wave_red(b0q); wave_red(btp); wave_red(btq);
    __shared__ float sm[4][7];
    const int wv = t >> 6, ln = t & 63;
    if (ln == 0){
        sm[wv][0] = P; sm[wv][1] = Q; sm[wv][2] = R;
        sm[wv][3] = b0p; sm[wv][4] = b0q; sm[wv][5] = btp; sm[wv][6] = btq;
    }
    __syncthreads();
    if (t == 0){
        float v[7];
        #pragma unroll
        for (int k = 0; k < 7; ++k)
            v[k] = sm[0][k] + sm[1][k] + sm[2][k] + sm[3][k];
        float so = sout[o]; float fo = floorf(so); float fro = so - fo;
        const float a0 = 1.f - fro, a1 = fro;
        const int j1 = (int)fo + 1;
        float sz, sq;
        if (j1 == 0){   // Z[t] = a0*Y[t-1](t>=1) + a1*Y[t]
            sz = a0 * (v[0] - v[5]) + a1 * v[0];
            sq = a0 * a0 * (v[1] - v[6]) + a1 * a1 * v[1] + 2.f * a0 * a1 * v[2];
        } else {        // Z[t] = a0*Y[t] + a1*Y[t+1](t<=T-2)
            sz = a0 * v[0] + a1 * (v[0] - v[3]);
            sq = a0 * a0 * v[1] + a1 * a1 * (v[1] - v[4]) + 2.f * a0 * a1 * v[2];
        }
        float mean = sz / NT;
        float var  = sq / NT - mean * mean;
        float rstd = rsqrtf(var + EPS);
        float sc = rstd * g2[o];
        s2[o] = sc;
        b2[o] = be2[o] - mean * sc;
    }
}

// ---------------- Pass 4: shift_out + BN2 + write fp32 output ------------------
// grid 512, 4-tile stride. Tile = 64 flat rows. Thread: 8 ch x 8 rows, 16B loads.
__global__ __launch_bounds__(256) void k_out(const ushort_t* __restrict__ Y,
                                             const float* __restrict__ s2,
                                             const float* __restrict__ b2,
                                             const float* __restrict__ sout,
                                             float* __restrict__ out){
    const int tid = threadIdx.x;
    const int c8 = (tid & 31) << 3, rg = tid >> 5;
    float sc[8], bs[8], a0[8], a1[8]; int j1[8];
    #pragma unroll
    for (int j = 0; j < 8; ++j){
        sc[j] = s2[c8 + j]; bs[j] = b2[c8 + j];
        float so = sout[c8 + j]; float fo = floorf(so); float fro = so - fo;
        a0[j] = 1.f - fro; a1[j] = fro; j1[j] = (int)fo + 1;
    }
    for (int g = 0; g < 4; ++g){
        const int tb = blockIdx.x + (g << 9);
        const int n = tb >> 4;
        const int rs = ((tb & 15) << 6) + (rg << 3);
        const ushort_t* yb = Y + ((size_t)n << 18) + c8;
        float* ob = out + ((size_t)n << 18) + c8;
        f32x4 m0 = {0.f,0.f,0.f,0.f}, m1 = m0, z0, z1;
        if (rs > 0) ld8bf(yb + ((size_t)(rs - 1) << 8), m0, m1);
        ld8bf(yb + ((size_t)rs << 8), z0, z1);
        #pragma unroll
        for (int k = 0; k < 8; ++k){
            const int t = rs + k;
            f32x4 p0 = {0.f,0.f,0.f,0.f}, p1 = p0;
            if (t < 1023) ld8bf(yb + ((size_t)(t + 1) << 8), p0, p1);
            f32x4 o0, o1;
            #pragma unroll
            for (int j = 0; j < 4; ++j){
                float zl = j1[j] ? z0[j] : m0[j];
                float zr = j1[j] ? p0[j] : z0[j];
                o0[j] = fmaf(a0[j] * zl + a1[j] * zr, sc[j], bs[j]);
                float zl2 = j1[4 + j] ? z1[j] : m1[j];
                float zr2 = j1[4 + j] ? p1[j] : z1[j];
                o1[j] = fmaf(a0[4 + j] * zl2 + a1[4 + j] * zr2, sc[4 + j], bs[4 + j]);
            }
            *(f32x4*)&ob[(size_t)t << 8] = o0;
            *(f32x4*)&ob[((size_t)t << 8) + 4] = o1;
            m0 = z0; m1 = z1; z0 = p0; z1 = p1;
        }
    }
}

extern "C" void kernel_launch(void* const* d_in, const int* in_sizes, int n_in,
                              void* d_out, int out_size, void* d_ws, size_t ws_size,
                              hipStream_t stream){
    const float* x    = (const float*)d_in[0];
    const float* g1   = (const float*)d_in[1];
    const float* be1  = (const float*)d_in[2];
    const float* sin_ = (const float*)d_in[3];
    const float* W    = (const float*)d_in[4];
    const float* cb   = (const float*)d_in[5];
    const float* sout = (const float*)d_in[6];
    const float* g2   = (const float*)d_in[7];
    const float* be2  = (const float*)d_in[8];
    float* out = (float*)d_out;

    char* ws = (char*)d_ws;
    ushort_t* Y  = (ushort_t*)ws;                       // 67108864 B
    ushort_t* WF = (ushort_t*)(ws + 67108864);          // 131072 B
    float* SP = (float*)(ws + 67239936);                // 2048*256 f32 each
    float* SQ = SP + 524288;
    float* SR = SQ + 524288;
    float* FR = SR + 524288;
    float* LR = FR + 524288;
    float* par = LR + 524288;
    float* s1    = par;         float* b1    = par + 256;
    float* s2    = par + 512;   float* b2    = par + 768;
    float* bias2 = par + 1024;  float* corr0 = par + 1280;
    float* corrT = par + 1536;
    // psum/psq alias Y (consumed by k_fin1 before k_conv writes Y)
    float* psum = (float*)ws;
    float* psq  = psum + 524288;
    // shifted bf16 raw-x lives in d_out (consumed by k_conv before k_out overwrites)
    ushort_t* xs = (ushort_t*)d_out;

    k_prep <<<512, 256, 0, stream>>>(x, sin_, xs, psum, psq);
    k_fin1 <<<256, 256, 0, stream>>>(psum, psq, g1, be1, s1, b1);
    k_w    <<<256, 256, 0, stream>>>(W, cb, s1, b1, sin_, WF, bias2, corr0, corrT);
    k_conv <<<512, 256, 0, stream>>>(xs, WF, bias2, corr0, corrT,
                                     Y, SP, SQ, SR, FR, LR);
    k_fin2 <<<256, 256, 0, stream>>>(SP, SQ, SR, FR, LR, g2, be2, sout, s2, b2);
    k_out  <<<512, 256, 0, stream>>>(Y, s2, b2, sout, out);
}

// Round 9
// 182.072 us; speedup vs baseline: 1.0257x; 1.0257x over previous
//
#include <hip/hip_runtime.h>
#include <stddef.h>

typedef __attribute__((ext_vector_type(8))) short short8;
typedef __attribute__((ext_vector_type(4))) float f32x4;
typedef __attribute__((ext_vector_type(2))) unsigned int u32x2;
typedef __attribute__((ext_vector_type(4))) unsigned int u32x4;
typedef unsigned short ushort_t;
typedef unsigned int uint_t;

#define TT 1024
#define NT 131072.0f   // N*T
#define EPS 1e-5f

__device__ __forceinline__ float bf2f(ushort_t u){
    union { float f; uint_t i; } v; v.i = ((uint_t)u) << 16; return v.f;
}
__device__ __forceinline__ ushort_t f2bf(float f){
    union { float f; uint_t i; } v; v.f = f;
    uint_t r = v.i + 0x7fffu + ((v.i >> 16) & 1u);
    return (ushort_t)(r >> 16);
}
__device__ __forceinline__ uint_t pack2(float lo, float hi){
    return (uint_t)f2bf(lo) | ((uint_t)f2bf(hi) << 16);
}
__device__ __forceinline__ f32x4 ld4bf(const ushort_t* p){
    u32x2 u = *(const u32x2*)p;
    f32x4 r;
    r[0] = bf2f((ushort_t)(u[0] & 0xffffu));
    r[1] = bf2f((ushort_t)(u[0] >> 16));
    r[2] = bf2f((ushort_t)(u[1] & 0xffffu));
    r[3] = bf2f((ushort_t)(u[1] >> 16));
    return r;
}
__device__ __forceinline__ void ld8bf(const ushort_t* p, f32x4& lo, f32x4& hi){
    u32x4 u = *(const u32x4*)p;
    lo[0] = bf2f((ushort_t)(u[0] & 0xffffu)); lo[1] = bf2f((ushort_t)(u[0] >> 16));
    lo[2] = bf2f((ushort_t)(u[1] & 0xffffu)); lo[3] = bf2f((ushort_t)(u[1] >> 16));
    hi[0] = bf2f((ushort_t)(u[2] & 0xffffu)); hi[1] = bf2f((ushort_t)(u[2] >> 16));
    hi[2] = bf2f((ushort_t)(u[3] & 0xffffu)); hi[3] = bf2f((ushort_t)(u[3] >> 16));
}
__device__ __forceinline__ void wave_red(float& v){
    #pragma unroll
    for (int off = 32; off > 0; off >>= 1) v += __shfl_down(v, off);
}
// async 16B global->LDS (width-16 DMA). LDS dest = wave-uniform base + lane*16.
__device__ __forceinline__ void dma16(const void* g, void* l){
    __builtin_amdgcn_global_load_lds(
        (const __attribute__((address_space(1))) unsigned int*)g,
        (__attribute__((address_space(3))) unsigned int*)l, 16, 0, 0);
}

// ---- Pass 1: per-channel stats of RAW x + shifted raw-x bf16 (pre-swizzled) ---
// grid 2048, block 256. Block b: 64 flat rows. Thread: 8 ch x 8 rows.
__global__ __launch_bounds__(256) void k_prep(const float* __restrict__ x,
                                              const float* __restrict__ sin_,
                                              ushort_t* __restrict__ xs,
                                              float* __restrict__ psum,
                                              float* __restrict__ psq){
    __shared__ float ls[8][256], lq[8][256];
    const int b = blockIdx.x, tid = threadIdx.x;
    const int c8 = (tid & 31) << 3, rg = tid >> 5;
    const size_t row0 = ((size_t)b << 6) + ((size_t)rg << 3);
    const int n = (int)(row0 >> 10), rt = (int)(row0 & 1023);
    const float* xp = x + ((size_t)n << 18) + c8;
    ushort_t* wp = xs + ((size_t)n << 18);
    float a0[8], a1[8]; int i1[8];
    #pragma unroll
    for (int j = 0; j < 8; ++j){
        float sv = sin_[c8 + j]; float fi = floorf(sv); float fr = sv - fi;
        a0[j] = 1.f - fr; a1[j] = fr; i1[j] = (int)fi + 1;
    }
    f32x4 s0 = {0.f,0.f,0.f,0.f}, s1v = s0, q0 = s0, q1 = s0;
    f32x4 Am = s0, Bm = s0, A0 = s0, B0 = s0;
    if (rt > 0){
        Am = *(const f32x4*)&xp[(size_t)(rt - 1) << 8];
        Bm = *(const f32x4*)&xp[((size_t)(rt - 1) << 8) + 4];
    }
    A0 = *(const f32x4*)&xp[(size_t)rt << 8];
    B0 = *(const f32x4*)&xp[((size_t)rt << 8) + 4];
    #pragma unroll
    for (int k = 0; k < 8; ++k){
        const int t = rt + k;
        f32x4 Ap = {0.f,0.f,0.f,0.f}, Bp = Ap;
        if (t < 1023){
            Ap = *(const f32x4*)&xp[(size_t)(t + 1) << 8];
            Bp = *(const f32x4*)&xp[((size_t)(t + 1) << 8) + 4];
        }
        float v[8];
        #pragma unroll
        for (int j = 0; j < 4; ++j){
            s0[j] += A0[j]; q0[j] = fmaf(A0[j], A0[j], q0[j]);
            s1v[j] += B0[j]; q1[j] = fmaf(B0[j], B0[j], q1[j]);
            float zl = i1[j] ? A0[j] : Am[j];
            float zr = i1[j] ? Ap[j] : A0[j];
            v[j] = a0[j] * zl + a1[j] * zr;
            float zl2 = i1[4 + j] ? B0[j] : Bm[j];
            float zr2 = i1[4 + j] ? Bp[j] : B0[j];
            v[4 + j] = a0[4 + j] * zl2 + a1[4 + j] * zr2;
        }
        u32x4 u;
        u[0] = pack2(v[0], v[1]); u[1] = pack2(v[2], v[3]);
        u[2] = pack2(v[4], v[5]); u[3] = pack2(v[6], v[7]);
        *(u32x4*)&wp[((size_t)t << 8) + (c8 ^ ((t & 7) << 3))] = u;
        Am = A0; Bm = B0; A0 = Ap; B0 = Bp;
    }
    #pragma unroll
    for (int j = 0; j < 4; ++j){
        ls[rg][c8 + j] = s0[j];     lq[rg][c8 + j] = q0[j];
        ls[rg][c8 + 4 + j] = s1v[j]; lq[rg][c8 + 4 + j] = q1[j];
    }
    __syncthreads();
    const int c = tid;
    float ps = 0.f, pq = 0.f;
    #pragma unroll
    for (int g = 0; g < 8; ++g){ ps += ls[g][c]; pq += lq[g][c]; }
    psum[(size_t)b * 256 + c] = ps;
    psq [(size_t)b * 256 + c] = pq;
}

// grid 256 (channel), block 256: reduce 2048 partials -> BN1 affine.
__global__ __launch_bounds__(256) void k_fin1(const float* __restrict__ psum,
                                              const float* __restrict__ psq,
                                              const float* __restrict__ g1,
                                              const float* __restrict__ be1,
                                              float* __restrict__ s1, float* __restrict__ b1){
    const int c = blockIdx.x, t = threadIdx.x;
    float s = 0.f, q = 0.f;
    #pragma unroll
    for (int i = 0; i < 8; ++i){
        const size_t b = (size_t)(t * 8 + i);
        s += psum[b * 256 + c]; q += psq[b * 256 + c];
    }
    wave_red(s); wave_red(q);
    __shared__ float sm[8];
    const int wv = t >> 6, ln = t & 63;
    if (ln == 0){ sm[wv] = s; sm[4 + wv] = q; }
    __syncthreads();
    if (t == 0){
        float S = sm[0] + sm[1] + sm[2] + sm[3];
        float Q = sm[4] + sm[5] + sm[6] + sm[7];
        float mean = S / NT;
        float var  = Q / NT - mean * mean;
        float rstd = rsqrtf(var + EPS);
        float sc = rstd * g1[c];
        s1[c] = sc;
        b1[c] = be1[c] - mean * sc;
    }
}

// ---- merged: WF fragments (W*s1 bf16) + bias2/corr0/corrT. grid 256 (o). ----
__global__ __launch_bounds__(256) void k_w(const float* __restrict__ W,
                                           const float* __restrict__ cb,
                                           const float* __restrict__ s1,
                                           const float* __restrict__ b1,
                                           const float* __restrict__ sin_,
                                           ushort_t* __restrict__ WF,
                                           float* __restrict__ bias2,
                                           float* __restrict__ corr0,
                                           float* __restrict__ corrT){
    const int o = blockIdx.x, c = threadIdx.x;
    const float w = W[(size_t)o * 256 + c];
    float sv = sin_[c]; float fi = floorf(sv); float fr = sv - fi;
    const float a0 = 1.f - fr, a1 = fr; const int i1 = (int)fi + 1;
    // fragment-major scatter: row=o, k=c
    const int ks = c >> 5, lg = (c & 31) >> 3, j = c & 7;
    WF[(size_t)(((ks * 16 + (o >> 4)) * 64 + lg * 16 + (o & 15)) * 8 + j)] = f2bf(w * s1[c]);
    float wb = w * b1[c];
    float c0 = (i1 == 0) ? wb * a0 : 0.f;
    float cT = (i1 == 1) ? wb * a1 : 0.f;
    wave_red(wb); wave_red(c0); wave_red(cT);
    __shared__ float sm[4][3];
    const int wv = c >> 6, ln = c & 63;
    if (ln == 0){ sm[wv][0] = wb; sm[wv][1] = c0; sm[wv][2] = cT; }
    __syncthreads();
    if (c == 0){
        bias2[o] = cb[o] + sm[0][0] + sm[1][0] + sm[2][0] + sm[3][0];
        corr0[o] = sm[0][1] + sm[1][1] + sm[2][1] + sm[3][1];
        corrT[o] = sm[0][2] + sm[1][2] + sm[2][2] + sm[3][2];
    }
}

// -------- Pass 2: GEMM, 8 waves/block, 2-phase vmcnt staging + BN2 partials ----
// grid 2048 = (n, t-tile of 64), block 512 (8 waves). Wave owns 32 o x 64 t.
__global__ __launch_bounds__(512, 8) void k_conv(const ushort_t* __restrict__ xs,
                                                 const ushort_t* __restrict__ WF,
                                                 const float* __restrict__ bias2,
                                                 const float* __restrict__ corr0,
                                                 const float* __restrict__ corrT,
                                                 ushort_t* __restrict__ Y,
                                                 float* __restrict__ SP, float* __restrict__ SQ,
                                                 float* __restrict__ SR,
                                                 float* __restrict__ FR, float* __restrict__ LR){
    __shared__ __align__(16) ushort_t lds[16384];   // 64 rows x 256 ush (swizzled)
    const int tid = threadIdx.x;
    const int n  = blockIdx.x >> 4;
    const int t0 = (blockIdx.x & 15) << 6;
    const int lane = tid & 63, wv = tid >> 6;       // 8 waves
    const int l15 = lane & 15, lg = lane >> 4;

    // ---- staging: half1 = rows [wv*4, wv*4+4), half2 = +32. 2+2 DMAs/wave ----
    {
        const ushort_t* gsrc = xs + ((size_t)n << 18) + ((size_t)(t0 + (wv << 2)) << 8);
        dma16(gsrc + (lane << 3),         &lds[(wv << 10)]);
        dma16(gsrc + 512 + (lane << 3),   &lds[(wv << 10) + 512]);
        const ushort_t* gsrc2 = gsrc + (32 << 8);
        dma16(gsrc2 + (lane << 3),        &lds[8192 + (wv << 10)]);
        dma16(gsrc2 + 512 + (lane << 3),  &lds[8192 + (wv << 10) + 512]);
    }

    // ---- MFMA: wave wv owns o in [wv*32, wv*32+32); phase A t<32, B t>=32 ----
    f32x4 acc[2][4];
    #pragma unroll
    for (int r = 0; r < 2; ++r)
        #pragma unroll
        for (int q = 0; q < 4; ++q)
            acc[r][q] = (f32x4){0.f, 0.f, 0.f, 0.f};

    const short8* wf8 = (const short8*)WF;
    #pragma unroll
    for (int half = 0; half < 2; ++half){
        if (half == 0) { asm volatile("s_waitcnt vmcnt(2)" ::: "memory"); }
        else           { asm volatile("s_waitcnt vmcnt(0)" ::: "memory"); }
        __builtin_amdgcn_sched_barrier(0);
        __builtin_amdgcn_s_barrier();
        #pragma unroll
        for (int ks = 0; ks < 8; ++ks){
            short8 aF[2], bF[2];
            #pragma unroll
            for (int r = 0; r < 2; ++r)
                aF[r] = wf8[(ks * 16 + (wv << 1) + r) * 64 + lane];
            const int kk = (ks << 5) + (lg << 3);
            #pragma unroll
            for (int qq = 0; qq < 2; ++qq){
                const int t = ((half * 2 + qq) << 4) | l15;
                bF[qq] = *(const short8*)&lds[(t << 8) + (kk ^ ((t & 7) << 3))];
            }
            #pragma unroll
            for (int r = 0; r < 2; ++r)
                #pragma unroll
                for (int qq = 0; qq < 2; ++qq)
                    acc[r][half * 2 + qq] =
                        __builtin_amdgcn_mfma_f32_16x16x32_bf16(aF[r], bF[qq],
                                                                acc[r][half * 2 + qq], 0, 0, 0);
        }
    }
    __syncthreads();

    // ---- epilogue: bias + boundary corr + relu -> LDS [t][o ^ ((t&7)<<3)] ----
    const bool isFirst = (t0 == 0), isLast = (t0 == 960);
    #pragma unroll
    for (int r = 0; r < 2; ++r){
        const int ob = (wv << 5) + (r << 4) + (lg << 2);
        const f32x4 cbv = *(const f32x4*)&bias2[ob];
        f32x4 c0v = {0.f,0.f,0.f,0.f}, cTv = {0.f,0.f,0.f,0.f};
        if (isFirst) c0v = *(const f32x4*)&corr0[ob];
        if (isLast)  cTv = *(const f32x4*)&corrT[ob];
        #pragma unroll
        for (int q = 0; q < 4; ++q){
            const int t = (q << 4) | l15;
            float v[4];
            #pragma unroll
            for (int j = 0; j < 4; ++j){
                float z = acc[r][q][j] + cbv[j];
                if (isFirst && t == 0)  z -= c0v[j];
                if (isLast  && t == 63) z -= cTv[j];
                v[j] = z > 0.f ? z : 0.f;
            }
            u32x2 w; w[0] = pack2(v[0], v[1]); w[1] = pack2(v[2], v[3]);
            *(u32x2*)&lds[(t << 8) + (ob ^ ((t & 7) << 3))] = w;
        }
    }
    __syncthreads();

    // ---- Y store (coalesced, de-swizzle on read) + FR/LR + in-tile stats ----
    u32x2* Yu = (u32x2*)Y;
    const size_t rbase = ((size_t)n << 10) + t0;
    #pragma unroll
    for (int it = 0; it < 8; ++it){
        const int row = (it << 3) + wv;
        u32x2 v = *(const u32x2*)&lds[(row << 8) + ((lane << 2) ^ ((row & 7) << 3))];
        Yu[((rbase + row) << 6) + lane] = v;
    }
    if (tid < 256){
        const int o = tid;
        FR[(size_t)blockIdx.x * 256 + o] = bf2f(lds[o]);
        LR[(size_t)blockIdx.x * 256 + o] = bf2f(lds[(63 << 8) + (o ^ 56)]);
    }
    f32x4 P = {0.f,0.f,0.f,0.f}, Q = P, R = P;
    {
        const int o4 = lane << 2;
        const int r0 = wv << 3;
        f32x4 prev = {0.f,0.f,0.f,0.f};
        if (wv > 0) prev = ld4bf(&lds[((r0 - 1) << 8) + (o4 ^ 56)]);
        #pragma unroll 8
        for (int k = 0; k < 8; ++k){
            const int t = r0 + k;
            f32x4 y = ld4bf(&lds[(t << 8) + (o4 ^ ((t & 7) << 3))]);
            #pragma unroll
            for (int j = 0; j < 4; ++j){
                P[j] += y[j];
                Q[j] = fmaf(y[j], y[j], Q[j]);
                R[j] = fmaf(prev[j], y[j], R[j]);
            }
            prev = y;
        }
    }
    __syncthreads();
    float* fl = (float*)lds;
    {
        const int o4 = lane << 2;
        *(f32x4*)&fl[wv * 768 + o4]       = P;
        *(f32x4*)&fl[wv * 768 + 256 + o4] = Q;
        *(f32x4*)&fl[wv * 768 + 512 + o4] = R;
    }
    __syncthreads();
    if (tid < 256){
        const int o = tid;
        float p = 0.f, q = 0.f, r = 0.f;
        #pragma unroll
        for (int g = 0; g < 8; ++g){
            p += fl[g * 768 + o];
            q += fl[g * 768 + 256 + o];
            r += fl[g * 768 + 512 + o];
        }
        const size_t idx = (size_t)blockIdx.x * 256 + o;
        SP[idx] = p; SQ[idx] = q; SR[idx] = r;
    }
}

// ---------------- Pass 3: assemble shifted BN2 stats ---------------------------
__global__ __launch_bounds__(256) void k_fin2(const float* __restrict__ SP,
                                              const float* __restrict__ SQ,
                                              const float* __restrict__ SR,
                                              const float* __restrict__ FR,
                                              const float* __restrict__ LR,
                                              const float* __restrict__ g2,
                                              const float* __restrict__ be2,
                                              const float* __restrict__ sout,
                                              float* __restrict__ s2, float* __restrict__ b2){
    const int o = blockIdx.x, t = threadIdx.x;
    float P = 0.f, Q = 0.f, R = 0.f, b0p = 0.f, b0q = 0.f, btp = 0.f, btq = 0.f;
    #pragma unroll
    for (int i = 0; i < 8; ++i){
        const int b = t * 8 + i;
        const size_t idx = (size_t)b * 256 + o;
        P += SP[idx]; Q += SQ[idx];
        float r = SR[idx];
        const float fr = FR[idx], lr = LR[idx];
        const int tile = b & 15;
        if (tile > 0) r = fmaf(LR[idx - 256], fr, r);
        R += r;
        if (tile == 0){ b0p += fr; b0q += fr * fr; }
        if (tile == 15){ btp += lr; btq += lr * lr; }
    }
    wave_red(P); wave_red(Q); wave_red(R);
    wave_red(b0p); wave_red(b0q); wave_red(btp); wave_red(btq);
    __shared__ float sm[4][7];
    const int wv = t >> 6, ln = t & 63;
    if (ln == 0){
        sm[wv][0] = P; sm[wv][1] = Q; sm[wv][2] = R;
        sm[wv][3] = b0p; sm[wv][4] = b0q; sm[wv][5] = btp; sm[wv][6] = btq;
    }
    __syncthreads();
    if (t == 0){
        float v[7];
        #pragma unroll
        for (int k = 0; k < 7; ++k)
            v[k] = sm[0][k] + sm[1][k] + sm[2][k] + sm[3][k];
        float so = sout[o]; float fo = floorf(so); float fro = so - fo;
        const float a0 = 1.f - fro, a1 = fro;
        const int j1 = (int)fo + 1;
        float sz, sq;
        if (j1 == 0){   // Z[t] = a0*Y[t-1](t>=1) + a1*Y[t]
            sz = a0 * (v[0] - v[5]) + a1 * v[0];
            sq = a0 * a0 * (v[1] - v[6]) + a1 * a1 * v[1] + 2.f * a0 * a1 * v[2];
        } else {        // Z[t] = a0*Y[t] + a1*Y[t+1](t<=T-2)
            sz = a0 * v[0] + a1 * (v[0] - v[3]);
            sq = a0 * a0 * v[1] + a1 * a1 * (v[1] - v[4]) + 2.f * a0 * a1 * v[2];
        }
        float mean = sz / NT;
        float var  = sq / NT - mean * mean;
        float rstd = rsqrtf(var + EPS);
        float sc = rstd * g2[o];
        s2[o] = sc;
        b2[o] = be2[o] - mean * sc;
    }
}

// ---------------- Pass 4: shift_out + BN2 + write fp32 output ------------------
// grid 2048 = (n, 1/16 of T), block 256. Thread: 8 ch x 8 rows, 16B Y loads.
__global__ __launch_bounds__(256) void k_out(const ushort_t* __restrict__ Y,
                                             const float* __restrict__ s2,
                                             const float* __restrict__ b2,
                                             const float* __restrict__ sout,
                                             float* __restrict__ out){
    const int b = blockIdx.x, tid = threadIdx.x;
    const int n = b >> 4, c8 = (tid & 31) << 3, rg = tid >> 5;
    const int rs = ((b & 15) << 6) + (rg << 3);
    float sc[8], bs[8], a0[8], a1[8]; int j1[8];
    #pragma unroll
    for (int j = 0; j < 8; ++j){
        sc[j] = s2[c8 + j]; bs[j] = b2[c8 + j];
        float so = sout[c8 + j]; float fo = floorf(so); float fro = so - fo;
        a0[j] = 1.f - fro; a1[j] = fro; j1[j] = (int)fo + 1;
    }
    const ushort_t* yb = Y + ((size_t)n << 18) + c8;
    float* ob = out + ((size_t)n << 18) + c8;
    f32x4 m0 = {0.f,0.f,0.f,0.f}, m1 = m0, z0, z1;
    if (rs > 0) ld8bf(yb + ((size_t)(rs - 1) << 8), m0, m1);
    ld8bf(yb + ((size_t)rs << 8), z0, z1);
    #pragma unroll
    for (int k = 0; k < 8; ++k){
        const int t = rs + k;
        f32x4 p0 = {0.f,0.f,0.f,0.f}, p1 = p0;
        if (t < 1023) ld8bf(yb + ((size_t)(t + 1) << 8), p0, p1);
        f32x4 o0, o1;
        #pragma unroll
        for (int j = 0; j < 4; ++j){
            float zl = j1[j] ? z0[j] : m0[j];
            float zr = j1[j] ? p0[j] : z0[j];
            o0[j] = fmaf(a0[j] * zl + a1[j] * zr, sc[j], bs[j]);
            float zl2 = j1[4 + j] ? z1[j] : m1[j];
            float zr2 = j1[4 + j] ? p1[j] : z1[j];
            o1[j] = fmaf(a0[4 + j] * zl2 + a1[4 + j] * zr2, sc[4 + j], bs[4 + j]);
        }
        *(f32x4*)&ob[(size_t)t << 8] = o0;
        *(f32x4*)&ob[((size_t)t << 8) + 4] = o1;
        m0 = z0; m1 = z1; z0 = p0; z1 = p1;
    }
}

extern "C" void kernel_launch(void* const* d_in, const int* in_sizes, int n_in,
                              void* d_out, int out_size, void* d_ws, size_t ws_size,
                              hipStream_t stream){
    const float* x    = (const float*)d_in[0];
    const float* g1   = (const float*)d_in[1];
    const float* be1  = (const float*)d_in[2];
    const float* sin_ = (const float*)d_in[3];
    const float* W    = (const float*)d_in[4];
    const float* cb   = (const float*)d_in[5];
    const float* sout = (const float*)d_in[6];
    const float* g2   = (const float*)d_in[7];
    const float* be2  = (const float*)d_in[8];
    float* out = (float*)d_out;

    char* ws = (char*)d_ws;
    ushort_t* Y  = (ushort_t*)ws;                       // 67108864 B
    ushort_t* WF = (ushort_t*)(ws + 67108864);          // 131072 B
    float* SP = (float*)(ws + 67239936);                // 2048*256 f32 each
    float* SQ = SP + 524288;
    float* SR = SQ + 524288;
    float* FR = SR + 524288;
    float* LR = FR + 524288;
    float* par = LR + 524288;
    float* s1    = par;         float* b1    = par + 256;
    float* s2    = par + 512;   float* b2    = par + 768;
    float* bias2 = par + 1024;  float* corr0 = par + 1280;
    float* corrT = par + 1536;
    // psum/psq alias Y (consumed by k_fin1 before k_conv writes Y)
    float* psum = (float*)ws;
    float* psq  = psum + 524288;
    // shifted bf16 raw-x lives in d_out (consumed by k_conv before k_out overwrites)
    ushort_t* xs = (ushort_t*)d_out;

    k_prep <<<2048, 256, 0, stream>>>(x, sin_, xs, psum, psq);
    k_fin1 <<<256, 256, 0, stream>>>(psum, psq, g1, be1, s1, b1);
    k_w    <<<256, 256, 0, stream>>>(W, cb, s1, b1, sin_, WF, bias2, corr0, corrT);
    k_conv <<<2048, 512, 0, stream>>>(xs, WF, bias2, corr0, corrT,
                                      Y, SP, SQ, SR, FR, LR);
    k_fin2 <<<256, 256, 0, stream>>>(SP, SQ, SR, FR, LR, g2, be2, sout, s2, b2);
    k_out  <<<2048, 256, 0, stream>>>(Y, s2, b2, sout, out);
}

// Round 10
// 154.837 us; speedup vs baseline: 1.2061x; 1.1759x over previous
//
#include <hip/hip_runtime.h>
#include <stddef.h>

typedef __attribute__((ext_vector_type(8))) short short8;
typedef __attribute__((ext_vector_type(4))) float f32x4;
typedef __attribute__((ext_vector_type(2))) unsigned int u32x2;
typedef __attribute__((ext_vector_type(4))) unsigned int u32x4;
typedef unsigned short ushort_t;
typedef unsigned int uint_t;

#define TT 1024
#define NT 131072.0f   // N*T
#define EPS 1e-5f

__device__ __forceinline__ float bf2f(ushort_t u){
    union { float f; uint_t i; } v; v.i = ((uint_t)u) << 16; return v.f;
}
__device__ __forceinline__ ushort_t f2bf(float f){
    union { float f; uint_t i; } v; v.f = f;
    uint_t r = v.i + 0x7fffu + ((v.i >> 16) & 1u);
    return (ushort_t)(r >> 16);
}
__device__ __forceinline__ uint_t pack2(float lo, float hi){
    return (uint_t)f2bf(lo) | ((uint_t)f2bf(hi) << 16);
}
__device__ __forceinline__ f32x4 ld4bf(const ushort_t* p){
    u32x2 u = *(const u32x2*)p;
    f32x4 r;
    r[0] = bf2f((ushort_t)(u[0] & 0xffffu));
    r[1] = bf2f((ushort_t)(u[0] >> 16));
    r[2] = bf2f((ushort_t)(u[1] & 0xffffu));
    r[3] = bf2f((ushort_t)(u[1] >> 16));
    return r;
}
__device__ __forceinline__ void ld8bf(const ushort_t* p, f32x4& lo, f32x4& hi){
    u32x4 u = *(const u32x4*)p;
    lo[0] = bf2f((ushort_t)(u[0] & 0xffffu)); lo[1] = bf2f((ushort_t)(u[0] >> 16));
    lo[2] = bf2f((ushort_t)(u[1] & 0xffffu)); lo[3] = bf2f((ushort_t)(u[1] >> 16));
    hi[0] = bf2f((ushort_t)(u[2] & 0xffffu)); hi[1] = bf2f((ushort_t)(u[2] >> 16));
    hi[2] = bf2f((ushort_t)(u[3] & 0xffffu)); hi[3] = bf2f((ushort_t)(u[3] >> 16));
}
__device__ __forceinline__ void wave_red(float& v){
    #pragma unroll
    for (int off = 32; off > 0; off >>= 1) v += __shfl_down(v, off);
}
// async 16B global->LDS (width-16 DMA). LDS dest = wave-uniform base + lane*16.
__device__ __forceinline__ void dma16(const void* g, void* l){
    __builtin_amdgcn_global_load_lds(
        (const __attribute__((address_space(1))) unsigned int*)g,
        (__attribute__((address_space(3))) unsigned int*)l, 16, 0, 0);
}

// ---- Pass 1: per-channel stats of RAW x + shifted raw-x bf16 (pre-swizzled) ---
// grid 2048, block 256. Block b: 64 flat rows. Thread: 8 ch x 8 rows.
__global__ __launch_bounds__(256) void k_prep(const float* __restrict__ x,
                                              const float* __restrict__ sin_,
                                              ushort_t* __restrict__ xs,
                                              float* __restrict__ psum,
                                              float* __restrict__ psq){
    __shared__ float ls[8][256], lq[8][256];
    const int b = blockIdx.x, tid = threadIdx.x;
    const int c8 = (tid & 31) << 3, rg = tid >> 5;
    const size_t row0 = ((size_t)b << 6) + ((size_t)rg << 3);
    const int n = (int)(row0 >> 10), rt = (int)(row0 & 1023);
    const float* xp = x + ((size_t)n << 18) + c8;
    ushort_t* wp = xs + ((size_t)n << 18);
    float a0[8], a1[8]; int i1[8];
    #pragma unroll
    for (int j = 0; j < 8; ++j){
        float sv = sin_[c8 + j]; float fi = floorf(sv); float fr = sv - fi;
        a0[j] = 1.f - fr; a1[j] = fr; i1[j] = (int)fi + 1;
    }
    f32x4 s0 = {0.f,0.f,0.f,0.f}, s1v = s0, q0 = s0, q1 = s0;
    f32x4 Am = s0, Bm = s0, A0 = s0, B0 = s0;
    if (rt > 0){
        Am = *(const f32x4*)&xp[(size_t)(rt - 1) << 8];
        Bm = *(const f32x4*)&xp[((size_t)(rt - 1) << 8) + 4];
    }
    A0 = *(const f32x4*)&xp[(size_t)rt << 8];
    B0 = *(const f32x4*)&xp[((size_t)rt << 8) + 4];
    #pragma unroll
    for (int k = 0; k < 8; ++k){
        const int t = rt + k;
        f32x4 Ap = {0.f,0.f,0.f,0.f}, Bp = Ap;
        if (t < 1023){
            Ap = *(const f32x4*)&xp[(size_t)(t + 1) << 8];
            Bp = *(const f32x4*)&xp[((size_t)(t + 1) << 8) + 4];
        }
        float v[8];
        #pragma unroll
        for (int j = 0; j < 4; ++j){
            s0[j] += A0[j]; q0[j] = fmaf(A0[j], A0[j], q0[j]);
            s1v[j] += B0[j]; q1[j] = fmaf(B0[j], B0[j], q1[j]);
            float zl = i1[j] ? A0[j] : Am[j];
            float zr = i1[j] ? Ap[j] : A0[j];
            v[j] = a0[j] * zl + a1[j] * zr;
            float zl2 = i1[4 + j] ? B0[j] : Bm[j];
            float zr2 = i1[4 + j] ? Bp[j] : B0[j];
            v[4 + j] = a0[4 + j] * zl2 + a1[4 + j] * zr2;
        }
        u32x4 u;
        u[0] = pack2(v[0], v[1]); u[1] = pack2(v[2], v[3]);
        u[2] = pack2(v[4], v[5]); u[3] = pack2(v[6], v[7]);
        *(u32x4*)&wp[((size_t)t << 8) + (c8 ^ ((t & 7) << 3))] = u;
        Am = A0; Bm = B0; A0 = Ap; B0 = Bp;
    }
    #pragma unroll
    for (int j = 0; j < 4; ++j){
        ls[rg][c8 + j] = s0[j];     lq[rg][c8 + j] = q0[j];
        ls[rg][c8 + 4 + j] = s1v[j]; lq[rg][c8 + 4 + j] = q1[j];
    }
    __syncthreads();
    const int c = tid;
    float ps = 0.f, pq = 0.f;
    #pragma unroll
    for (int g = 0; g < 8; ++g){ ps += ls[g][c]; pq += lq[g][c]; }
    psum[(size_t)b * 256 + c] = ps;
    psq [(size_t)b * 256 + c] = pq;
}

// grid 256 (channel), block 256: reduce 2048 partials -> BN1 affine.
__global__ __launch_bounds__(256) void k_fin1(const float* __restrict__ psum,
                                              const float* __restrict__ psq,
                                              const float* __restrict__ g1,
                                              const float* __restrict__ be1,
                                              float* __restrict__ s1, float* __restrict__ b1){
    const int c = blockIdx.x, t = threadIdx.x;
    float s = 0.f, q = 0.f;
    #pragma unroll
    for (int i = 0; i < 8; ++i){
        const size_t b = (size_t)(t * 8 + i);
        s += psum[b * 256 + c]; q += psq[b * 256 + c];
    }
    wave_red(s); wave_red(q);
    __shared__ float sm[8];
    const int wv = t >> 6, ln = t & 63;
    if (ln == 0){ sm[wv] = s; sm[4 + wv] = q; }
    __syncthreads();
    if (t == 0){
        float S = sm[0] + sm[1] + sm[2] + sm[3];
        float Q = sm[4] + sm[5] + sm[6] + sm[7];
        float mean = S / NT;
        float var  = Q / NT - mean * mean;
        float rstd = rsqrtf(var + EPS);
        float sc = rstd * g1[c];
        s1[c] = sc;
        b1[c] = be1[c] - mean * sc;
    }
}

// ---- merged: WF fragments (W*s1 bf16) + bias2/corr0/corrT. grid 256 (o). ----
__global__ __launch_bounds__(256) void k_w(const float* __restrict__ W,
                                           const float* __restrict__ cb,
                                           const float* __restrict__ s1,
                                           const float* __restrict__ b1,
                                           const float* __restrict__ sin_,
                                           ushort_t* __restrict__ WF,
                                           float* __restrict__ bias2,
                                           float* __restrict__ corr0,
                                           float* __restrict__ corrT){
    const int o = blockIdx.x, c = threadIdx.x;
    const float w = W[(size_t)o * 256 + c];
    float sv = sin_[c]; float fi = floorf(sv); float fr = sv - fi;
    const float a0 = 1.f - fr, a1 = fr; const int i1 = (int)fi + 1;
    // fragment-major scatter: row=o, k=c
    const int ks = c >> 5, lg = (c & 31) >> 3, j = c & 7;
    WF[(size_t)(((ks * 16 + (o >> 4)) * 64 + lg * 16 + (o & 15)) * 8 + j)] = f2bf(w * s1[c]);
    float wb = w * b1[c];
    float c0 = (i1 == 0) ? wb * a0 : 0.f;
    float cT = (i1 == 1) ? wb * a1 : 0.f;
    wave_red(wb); wave_red(c0); wave_red(cT);
    __shared__ float sm[4][3];
    const int wv = c >> 6, ln = c & 63;
    if (ln == 0){ sm[wv][0] = wb; sm[wv][1] = c0; sm[wv][2] = cT; }
    __syncthreads();
    if (c == 0){
        bias2[o] = cb[o] + sm[0][0] + sm[1][0] + sm[2][0] + sm[3][0];
        corr0[o] = sm[0][1] + sm[1][1] + sm[2][1] + sm[3][1];
        corrT[o] = sm[0][2] + sm[1][2] + sm[2][2] + sm[3][2];
    }
}

// -------- Pass 2: GEMM, 8 waves (bounds 512,4 -> no spill) + BN2 partials ------
// grid 2048 = (n, t-tile of 64), block 512 (8 waves). Wave owns 32 o x 64 t.
__global__ __launch_bounds__(512, 4) void k_conv(const ushort_t* __restrict__ xs,
                                                 const ushort_t* __restrict__ WF,
                                                 const float* __restrict__ bias2,
                                                 const float* __restrict__ corr0,
                                                 const float* __restrict__ corrT,
                                                 ushort_t* __restrict__ Y,
                                                 float* __restrict__ SP, float* __restrict__ SQ,
                                                 float* __restrict__ SR,
                                                 float* __restrict__ FR, float* __restrict__ LR){
    __shared__ __align__(16) ushort_t lds[16384];   // 64 rows x 256 ush (swizzled)
    const int tid = threadIdx.x;
    const int n  = blockIdx.x >> 4;
    const int t0 = (blockIdx.x & 15) << 6;
    const int lane = tid & 63, wv = tid >> 6;       // 8 waves
    const int l15 = lane & 15, lg = lane >> 4;

    // ---- staging: wave wv copies rows [wv*8, wv*8+8) = 4 x 1KB DMA ----
    {
        const ushort_t* gsrc = xs + ((size_t)n << 18) + ((size_t)(t0 + (wv << 3)) << 8);
        #pragma unroll
        for (int i = 0; i < 4; ++i)
            dma16(gsrc + (i << 9) + (lane << 3), &lds[(wv << 11) + (i << 9)]);
    }
    __syncthreads();

    // ---- MFMA: wave wv owns o in [wv*32, wv*32+32) x 64 t ----
    f32x4 acc[2][4];
    #pragma unroll
    for (int r = 0; r < 2; ++r)
        #pragma unroll
        for (int q = 0; q < 4; ++q)
            acc[r][q] = (f32x4){0.f, 0.f, 0.f, 0.f};

    const short8* wf8 = (const short8*)WF;
    #pragma unroll
    for (int ks = 0; ks < 8; ++ks){
        short8 aF[2], bF[4];
        #pragma unroll
        for (int r = 0; r < 2; ++r)
            aF[r] = wf8[(ks * 16 + (wv << 1) + r) * 64 + lane];
        const int kk = (ks << 5) + (lg << 3);
        #pragma unroll
        for (int q = 0; q < 4; ++q){
            const int t = (q << 4) | l15;
            bF[q] = *(const short8*)&lds[(t << 8) + (kk ^ ((t & 7) << 3))];
        }
        #pragma unroll
        for (int r = 0; r < 2; ++r)
            #pragma unroll
            for (int q = 0; q < 4; ++q)
                acc[r][q] = __builtin_amdgcn_mfma_f32_16x16x32_bf16(aF[r], bF[q], acc[r][q], 0, 0, 0);
    }
    __syncthreads();

    // ---- epilogue: bias + boundary corr + relu -> LDS [t][o ^ ((t&7)<<3)] ----
    const bool isFirst = (t0 == 0), isLast = (t0 == 960);
    #pragma unroll
    for (int r = 0; r < 2; ++r){
        const int ob = (wv << 5) + (r << 4) + (lg << 2);
        const f32x4 cbv = *(const f32x4*)&bias2[ob];
        f32x4 c0v = {0.f,0.f,0.f,0.f}, cTv = {0.f,0.f,0.f,0.f};
        if (isFirst) c0v = *(const f32x4*)&corr0[ob];
        if (isLast)  cTv = *(const f32x4*)&corrT[ob];
        #pragma unroll
        for (int q = 0; q < 4; ++q){
            const int t = (q << 4) | l15;
            float v[4];
            #pragma unroll
            for (int j = 0; j < 4; ++j){
                float z = acc[r][q][j] + cbv[j];
                if (isFirst && t == 0)  z -= c0v[j];
                if (isLast  && t == 63) z -= cTv[j];
                v[j] = z > 0.f ? z : 0.f;
            }
            u32x2 w; w[0] = pack2(v[0], v[1]); w[1] = pack2(v[2], v[3]);
            *(u32x2*)&lds[(t << 8) + (ob ^ ((t & 7) << 3))] = w;
        }
    }
    __syncthreads();

    // ---- Y store (coalesced, de-swizzle on read) + FR/LR + in-tile stats ----
    u32x2* Yu = (u32x2*)Y;
    const size_t rbase = ((size_t)n << 10) + t0;
    #pragma unroll
    for (int it = 0; it < 8; ++it){
        const int row = (it << 3) + wv;
        u32x2 v = *(const u32x2*)&lds[(row << 8) + ((lane << 2) ^ ((row & 7) << 3))];
        Yu[((rbase + row) << 6) + lane] = v;
    }
    if (tid < 256){
        const int o = tid;
        FR[(size_t)blockIdx.x * 256 + o] = bf2f(lds[o]);
        LR[(size_t)blockIdx.x * 256 + o] = bf2f(lds[(63 << 8) + (o ^ 56)]);
    }
    f32x4 P = {0.f,0.f,0.f,0.f}, Q = P, R = P;
    {
        const int o4 = lane << 2;
        const int r0 = wv << 3;
        f32x4 prev = {0.f,0.f,0.f,0.f};
        if (wv > 0) prev = ld4bf(&lds[((r0 - 1) << 8) + (o4 ^ 56)]);
        #pragma unroll 8
        for (int k = 0; k < 8; ++k){
            const int t = r0 + k;
            f32x4 y = ld4bf(&lds[(t << 8) + (o4 ^ ((t & 7) << 3))]);
            #pragma unroll
            for (int j = 0; j < 4; ++j){
                P[j] += y[j];
                Q[j] = fmaf(y[j], y[j], Q[j]);
                R[j] = fmaf(prev[j], y[j], R[j]);
            }
            prev = y;
        }
    }
    __syncthreads();
    float* fl = (float*)lds;
    {
        const int o4 = lane << 2;
        *(f32x4*)&fl[wv * 768 + o4]       = P;
        *(f32x4*)&fl[wv * 768 + 256 + o4] = Q;
        *(f32x4*)&fl[wv * 768 + 512 + o4] = R;
    }
    __syncthreads();
    if (tid < 256){
        const int o = tid;
        float p = 0.f, q = 0.f, r = 0.f;
        #pragma unroll
        for (int g = 0; g < 8; ++g){
            p += fl[g * 768 + o];
            q += fl[g * 768 + 256 + o];
            r += fl[g * 768 + 512 + o];
        }
        const size_t idx = (size_t)blockIdx.x * 256 + o;
        SP[idx] = p; SQ[idx] = q; SR[idx] = r;
    }
}

// ---------------- Pass 3: assemble shifted BN2 stats ---------------------------
__global__ __launch_bounds__(256) void k_fin2(const float* __restrict__ SP,
                                              const float* __restrict__ SQ,
                                              const float* __restrict__ SR,
                                              const float* __restrict__ FR,
                                              const float* __restrict__ LR,
                                              const float* __restrict__ g2,
                                              const float* __restrict__ be2,
                                              const float* __restrict__ sout,
                                              float* __restrict__ s2, float* __restrict__ b2){
    const int o = blockIdx.x, t = threadIdx.x;
    float P = 0.f, Q = 0.f, R = 0.f, b0p = 0.f, b0q = 0.f, btp = 0.f, btq = 0.f;
    #pragma unroll
    for (int i = 0; i < 8; ++i){
        const int b = t * 8 + i;
        const size_t idx = (size_t)b * 256 + o;
        P += SP[idx]; Q += SQ[idx];
        float r = SR[idx];
        const float fr = FR[idx], lr = LR[idx];
        const int tile = b & 15;
        if (tile > 0) r = fmaf(LR[idx - 256], fr, r);
        R += r;
        if (tile == 0){ b0p += fr; b0q += fr * fr; }
        if (tile == 15){ btp += lr; btq += lr * lr; }
    }
    wave_red(P); wave_red(Q); wave_red(R);
    wave_red(b0p); wave_red(b0q); wave_red(btp); wave_red(btq);
    __shared__ float sm[4][7];
    const int wv = t >> 6, ln = t & 63;
    if (ln == 0){
        sm[wv][0] = P; sm[wv][1] = Q; sm[wv][2] = R;
        sm[wv][3] = b0p; sm[wv][4] = b0q; sm[wv][5] = btp; sm[wv][6] = btq;
    }
    __syncthreads();
    if (t == 0){
        float v[7];
        #pragma unroll
        for (int k = 0; k < 7; ++k)
            v[k] = sm[0][k] + sm[1][k] + sm[2][k] + sm[3][k];
        float so = sout[o]; float fo = floorf(so); float fro = so - fo;
        const float a0 = 1.f - fro, a1 = fro;
        const int j1 = (int)fo + 1;
        float sz, sq;
        if (j1 == 0){   // Z[t] = a0*Y[t-1](t>=1) + a1*Y[t]
            sz = a0 * (v[0] - v[5]) + a1 * v[0];
            sq = a0 * a0 * (v[1] - v[6]) + a1 * a1 * v[1] + 2.f * a0 * a1 * v[2];
        } else {        // Z[t] = a0*Y[t] + a1*Y[t+1](t<=T-2)
            sz = a0 * v[0] + a1 * (v[0] - v[3]);
            sq = a0 * a0 * v[1] + a1 * a1 * (v[1] - v[4]) + 2.f * a0 * a1 * v[2];
        }
        float mean = sz / NT;
        float var  = sq / NT - mean * mean;
        float rstd = rsqrtf(var + EPS);
        float sc = rstd * g2[o];
        s2[o] = sc;
        b2[o] = be2[o] - mean * sc;
    }
}

// ---------------- Pass 4: shift_out + BN2 + write fp32 output ------------------
// grid 2048 = (n, 1/16 of T), block 256. Thread: 8 ch x 8 rows, 16B Y loads.
__global__ __launch_bounds__(256) void k_out(const ushort_t* __restrict__ Y,
                                             const float* __restrict__ s2,
                                             const float* __restrict__ b2,
                                             const float* __restrict__ sout,
                                             float* __restrict__ out){
    const int b = blockIdx.x, tid = threadIdx.x;
    const int n = b >> 4, c8 = (tid & 31) << 3, rg = tid >> 5;
    const int rs = ((b & 15) << 6) + (rg << 3);
    float sc[8], bs[8], a0[8], a1[8]; int j1[8];
    #pragma unroll
    for (int j = 0; j < 8; ++j){
        sc[j] = s2[c8 + j]; bs[j] = b2[c8 + j];
        float so = sout[c8 + j]; float fo = floorf(so); float fro = so - fo;
        a0[j] = 1.f - fro; a1[j] = fro; j1[j] = (int)fo + 1;
    }
    const ushort_t* yb = Y + ((size_t)n << 18) + c8;
    float* ob = out + ((size_t)n << 18) + c8;
    f32x4 m0 = {0.f,0.f,0.f,0.f}, m1 = m0, z0, z1;
    if (rs > 0) ld8bf(yb + ((size_t)(rs - 1) << 8), m0, m1);
    ld8bf(yb + ((size_t)rs << 8), z0, z1);
    #pragma unroll
    for (int k = 0; k < 8; ++k){
        const int t = rs + k;
        f32x4 p0 = {0.f,0.f,0.f,0.f}, p1 = p0;
        if (t < 1023) ld8bf(yb + ((size_t)(t + 1) << 8), p0, p1);
        f32x4 o0, o1;
        #pragma unroll
        for (int j = 0; j < 4; ++j){
            float zl = j1[j] ? z0[j] : m0[j];
            float zr = j1[j] ? p0[j] : z0[j];
            o0[j] = fmaf(a0[j] * zl + a1[j] * zr, sc[j], bs[j]);
            float zl2 = j1[4 + j] ? z1[j] : m1[j];
            float zr2 = j1[4 + j] ? p1[j] : z1[j];
            o1[j] = fmaf(a0[4 + j] * zl2 + a1[4 + j] * zr2, sc[4 + j], bs[4 + j]);
        }
        *(f32x4*)&ob[(size_t)t << 8] = o0;
        *(f32x4*)&ob[((size_t)t << 8) + 4] = o1;
        m0 = z0; m1 = z1; z0 = p0; z1 = p1;
    }
}

extern "C" void kernel_launch(void* const* d_in, const int* in_sizes, int n_in,
                              void* d_out, int out_size, void* d_ws, size_t ws_size,
                              hipStream_t stream){
    const float* x    = (const float*)d_in[0];
    const float* g1   = (const float*)d_in[1];
    const float* be1  = (const float*)d_in[2];
    const float* sin_ = (const float*)d_in[3];
    const float* W    = (const float*)d_in[4];
    const float* cb   = (const float*)d_in[5];
    const float* sout = (const float*)d_in[6];
    const float* g2   = (const float*)d_in[7];
    const float* be2  = (const float*)d_in[8];
    float* out = (float*)d_out;

    char* ws = (char*)d_ws;
    ushort_t* Y  = (ushort_t*)ws;                       // 67108864 B
    ushort_t* WF = (ushort_t*)(ws + 67108864);          // 131072 B
    float* SP = (float*)(ws + 67239936);                // 2048*256 f32 each
    float* SQ = SP + 524288;
    float* SR = SQ + 524288;
    float* FR = SR + 524288;
    float* LR = FR + 524288;
    float* par = LR + 524288;
    float* s1    = par;         float* b1    = par + 256;
    float* s2    = par + 512;   float* b2    = par + 768;
    float* bias2 = par + 1024;  float* corr0 = par + 1280;
    float* corrT = par + 1536;
    // psum/psq alias Y (consumed by k_fin1 before k_conv writes Y)
    float* psum = (float*)ws;
    float* psq  = psum + 524288;
    // shifted bf16 raw-x lives in d_out (consumed by k_conv before k_out overwrites)
    ushort_t* xs = (ushort_t*)d_out;

    k_prep <<<2048, 256, 0, stream>>>(x, sin_, xs, psum, psq);
    k_fin1 <<<256, 256, 0, stream>>>(psum, psq, g1, be1, s1, b1);
    k_w    <<<256, 256, 0, stream>>>(W, cb, s1, b1, sin_, WF, bias2, corr0, corrT);
    k_conv <<<2048, 512, 0, stream>>>(xs, WF, bias2, corr0, corrT,
                                      Y, SP, SQ, SR, FR, LR);
    k_fin2 <<<256, 256, 0, stream>>>(SP, SQ, SR, FR, LR, g2, be2, sout, s2, b2);
    k_out  <<<2048, 256, 0, stream>>>(Y, s2, b2, sout, out);
}